// Round 6
// baseline (433.737 us; speedup 1.0000x reference)
//
#include <hip/hip_runtime.h>

typedef unsigned short ushort;
typedef unsigned int uint;
typedef __attribute__((ext_vector_type(8))) short short8;
typedef __attribute__((ext_vector_type(4))) float float4v;

#define D_MODEL 1024
#define NH 16
#define DH 64
#define BATCH 2
#define SEQ 1024
#define MEMLEN 1024
#define TOT 2048

__device__ __forceinline__ float b2f(ushort u) {
  return __uint_as_float(((uint)u) << 16);
}
__device__ __forceinline__ ushort f2b(float f) {
  uint i = __float_as_uint(f);
  uint r = (i + 0x7fffu + ((i >> 16) & 1u)) >> 16;
  return (ushort)r;
}
__device__ __forceinline__ void gld16(const ushort* g, ushort* l) {
  __builtin_amdgcn_global_load_lds(
      (const __attribute__((address_space(1))) void*)g,
      (__attribute__((address_space(3))) void*)l, 16, 0, 0);
}

// ------------------------------------------------- concat + cast to bf16 ----
__global__ __launch_bounds__(256) void concat_cvt_kernel(
    const float* __restrict__ x, const float* __restrict__ mem,
    ushort* __restrict__ xt, ushort* __restrict__ xb) {
  int idx = blockIdx.x * 256 + threadIdx.x;
  int row = idx >> 7;
  int c8 = (idx & 127) << 3;
  int b = row >> 11;
  int i = row & 2047;
  const float* src = (i < MEMLEN) ? &mem[((b << 10) + i) * D_MODEL]
                                  : &x[((b << 10) + (i - MEMLEN)) * D_MODEL];
  float4 f0 = *(const float4*)(&src[c8]);
  float4 f1 = *(const float4*)(&src[c8 + 4]);
  ushort u[8] = {f2b(f0.x), f2b(f0.y), f2b(f0.z), f2b(f0.w),
                 f2b(f1.x), f2b(f1.y), f2b(f1.z), f2b(f1.w)};
  *(uint4*)(&xt[row * D_MODEL + c8]) = *(const uint4*)u;
  if (i >= MEMLEN)
    *(uint4*)(&xb[((b << 10) + (i - MEMLEN)) * D_MODEL + c8]) = *(const uint4*)u;
}

// --------------------------------------------------- fp32 -> bf16 cast ------
__global__ __launch_bounds__(256) void cvt_kernel(const float* __restrict__ in,
                                                  ushort* __restrict__ out) {
  int idx = blockIdx.x * 256 + threadIdx.x;
  int base = idx << 3;
  float4 f0 = *(const float4*)(&in[base]);
  float4 f1 = *(const float4*)(&in[base + 4]);
  ushort u[8] = {f2b(f0.x), f2b(f0.y), f2b(f0.z), f2b(f0.w),
                 f2b(f1.x), f2b(f1.y), f2b(f1.z), f2b(f1.w)};
  *(uint4*)(&out[base]) = *(const uint4*)u;
}

// --------------------- mask -> bf16 pre-multiplied by -1e9 ------------------
__global__ __launch_bounds__(256) void maskcvt_kernel(
    const float* __restrict__ in, ushort* __restrict__ out) {
  int idx = blockIdx.x * 256 + threadIdx.x;
  int base = idx << 3;
  float4 f0 = *(const float4*)(&in[base]);
  float4 f1 = *(const float4*)(&in[base + 4]);
  ushort u[8] = {f2b(f0.x * -1e9f), f2b(f0.y * -1e9f), f2b(f0.z * -1e9f),
                 f2b(f0.w * -1e9f), f2b(f1.x * -1e9f), f2b(f1.y * -1e9f),
                 f2b(f1.z * -1e9f), f2b(f1.w * -1e9f)};
  *(uint4*)(&out[base]) = *(const uint4*)u;
}

// --------------------------- 5x transpose + cast to bf16 (one launch) -------
__global__ __launch_bounds__(256) void transpose_cvt5_kernel(
    const float* __restrict__ W0, const float* __restrict__ W1,
    const float* __restrict__ W2, const float* __restrict__ W3,
    const float* __restrict__ W4, ushort* __restrict__ T0,
    ushort* __restrict__ T1, ushort* __restrict__ T2, ushort* __restrict__ T3,
    ushort* __restrict__ T4) {
  __shared__ ushort tle[32][33];
  const float* W;
  ushort* T;
  switch (blockIdx.z) {
    case 0: W = W0; T = T0; break;
    case 1: W = W1; T = T1; break;
    case 2: W = W2; T = T2; break;
    case 3: W = W3; T = T3; break;
    default: W = W4; T = T4; break;
  }
  const int bx = blockIdx.x * 32, by = blockIdx.y * 32;
  const int tx = threadIdx.x & 31, ty = threadIdx.x >> 5;
#pragma unroll
  for (int j = 0; j < 32; j += 8)
    tle[ty + j][tx] = f2b(W[(by + ty + j) * 1024 + bx + tx]);
  __syncthreads();
#pragma unroll
  for (int j = 0; j < 32; j += 8)
    T[(bx + ty + j) * 1024 + by + tx] = tle[tx][ty + j];
}

// ------------------------------------- V transpose: kv cols -> vt[b][d][t] --
__global__ __launch_bounds__(256) void vtrans_kernel(
    const ushort* __restrict__ kv, ushort* __restrict__ vt) {
  __shared__ ushort tle[32][76];
  const int gx = blockIdx.x;   // 32-row (b,t) tiles
  const int gy = blockIdx.y;   // 64-wide d tiles
  const int tid = threadIdx.x;
  const int r = tid >> 3, c8 = (tid & 7) * 8;
  *(uint4*)(&tle[r][c8]) =
      *(const uint4*)(&kv[(gx * 32 + r) * 2048 + 1024 + gy * 64 + c8]);
  __syncthreads();
  const int dr = tid >> 2, tc8 = (tid & 3) * 8;
  const int bb = (gx * 32) >> 11, tbase = (gx * 32) & 2047;
  ushort tmp[8];
#pragma unroll
  for (int j = 0; j < 8; ++j) tmp[j] = tle[tc8 + j][dr];
  *(uint4*)(&vt[((bb << 10) + gy * 64 + dr) * 2048 + tbase + tc8]) =
      *(const uint4*)tmp;
}

// -------------------------------------------------- 128x128 m97-style GEMM --
// C[M x N] = A @ BT^T + bias, bf16 out. bias: col<1024 -> b0 else b1[col-1024].
__global__ __launch_bounds__(256) void gemm128_kernel(
    const ushort* __restrict__ A, const ushort* __restrict__ BT,
    const float* __restrict__ b0, const float* __restrict__ b1,
    ushort* __restrict__ Cout, int M, int N, int K) {
  __shared__ ushort As[128 * 32];
  __shared__ ushort Bs[128 * 32];
  const int m0 = blockIdx.x * 128, n0 = blockIdx.y * 128;
  const int tid = threadIdx.x;
  const int w = tid >> 6, lane = tid & 63, m15 = lane & 15, q4 = lane >> 4;
  const int wm = w & 1, wn = w >> 1;
  float4v acc[4][4] = {};
  const int c0 = tid, c1 = tid + 256;
  const int r0 = c0 >> 2, u0 = (c0 & 3) * 8;
  const int r1 = c1 >> 2, u1 = (c1 & 3) * 8;

  for (int kk = 0; kk < K; kk += 32) {
    __syncthreads();
    gld16(&A[(m0 + r0) * K + kk + u0], &As[c0 * 8]);
    gld16(&A[(m0 + r1) * K + kk + u1], &As[c1 * 8]);
    gld16(&BT[(n0 + r0) * K + kk + u0], &Bs[c0 * 8]);
    gld16(&BT[(n0 + r1) * K + kk + u1], &Bs[c1 * 8]);
    __syncthreads();
    short8 af[4], bf[4];
#pragma unroll
    for (int i = 0; i < 4; ++i)
      af[i] = *(const short8*)(&As[(wm * 64 + i * 16 + m15) * 32 + q4 * 8]);
#pragma unroll
    for (int j = 0; j < 4; ++j)
      bf[j] = *(const short8*)(&Bs[(wn * 64 + j * 16 + m15) * 32 + q4 * 8]);
#pragma unroll
    for (int i = 0; i < 4; ++i)
#pragma unroll
      for (int j = 0; j < 4; ++j)
        acc[i][j] =
            __builtin_amdgcn_mfma_f32_16x16x32_bf16(af[i], bf[j], acc[i][j], 0, 0, 0);
  }
#pragma unroll
  for (int j = 0; j < 4; ++j) {
    int col = n0 + wn * 64 + j * 16 + m15;
    float bv = (col < 1024) ? b0[col] : b1[col - 1024];
#pragma unroll
    for (int i = 0; i < 4; ++i) {
      int rowb = m0 + wm * 64 + i * 16 + q4 * 4;
#pragma unroll
      for (int r = 0; r < 4; ++r)
        Cout[(rowb + r) * N + col] = f2b(acc[i][j][r] + bv);
    }
  }
}

// -------------------------------------- 64x128-tile GEMM (for small M) ------
// B/bias selected by row half (m0 < rowSplit). EPI 0: bf16, 1: fp32.
template <int EPI>
__global__ __launch_bounds__(256) void gemm64_kernel(
    const ushort* __restrict__ A, const ushort* __restrict__ BT0,
    const ushort* __restrict__ BT1, int rowSplit, const float* __restrict__ b0,
    const float* __restrict__ b1, void* __restrict__ Cout, int M, int N, int K) {
  __shared__ ushort As[64 * 32];
  __shared__ ushort Bs[128 * 32];
  const int m0 = blockIdx.x * 64, n0 = blockIdx.y * 128;
  const ushort* BT = (m0 < rowSplit) ? BT0 : BT1;
  const float* bias = (m0 < rowSplit) ? b0 : b1;
  const int tid = threadIdx.x;
  const int w = tid >> 6, lane = tid & 63, m15 = lane & 15, q4 = lane >> 4;
  float4v acc[4][2] = {};
  const int ra = tid >> 2, ua = (tid & 3) * 8;
  const int c0 = tid, c1 = tid + 256;
  const int rb0 = c0 >> 2, ub0 = (c0 & 3) * 8;
  const int rb1 = c1 >> 2, ub1 = (c1 & 3) * 8;

  for (int kk = 0; kk < K; kk += 32) {
    __syncthreads();
    gld16(&A[(m0 + ra) * K + kk + ua], &As[tid * 8]);
    gld16(&BT[(n0 + rb0) * K + kk + ub0], &Bs[c0 * 8]);
    gld16(&BT[(n0 + rb1) * K + kk + ub1], &Bs[c1 * 8]);
    __syncthreads();
    short8 bf[2];
#pragma unroll
    for (int j = 0; j < 2; ++j)
      bf[j] = *(const short8*)(&Bs[(w * 32 + j * 16 + m15) * 32 + q4 * 8]);
#pragma unroll
    for (int i = 0; i < 4; ++i) {
      short8 af = *(const short8*)(&As[(i * 16 + m15) * 32 + q4 * 8]);
#pragma unroll
      for (int j = 0; j < 2; ++j)
        acc[i][j] =
            __builtin_amdgcn_mfma_f32_16x16x32_bf16(af, bf[j], acc[i][j], 0, 0, 0);
    }
  }
#pragma unroll
  for (int j = 0; j < 2; ++j) {
    int col = n0 + w * 32 + j * 16 + m15;
    float bv = bias[col];
#pragma unroll
    for (int i = 0; i < 4; ++i) {
      int rowb = m0 + i * 16 + q4 * 4;
#pragma unroll
      for (int r = 0; r < 4; ++r) {
        float v = acc[i][j][r] + bv;
        if (EPI == 1)
          ((float*)Cout)[(rowb + r) * N + col] = v;
        else
          ((ushort*)Cout)[(rowb + r) * N + col] = f2b(v);
      }
    }
  }
}

// -------------------------- barrier-free fused MFMA flash attention ---------
// Block = 4 waves, each wave independent: s-tile (16 rows) x T-half (1024).
// Global->VGPR fragment loads (no shared staging); wave-private LDS for the
// B-hat diagonal remap and the P C->A layout transpose (per-wave LDS ops are
// in-order: no barriers in the chunk loop). u = t-s+1023; main q[s].Qr[u]
// (u<2048); u==2048 -> 0; wrap q[s+1].Qr[u-2049] (u>2049). Main scatter '='
// first, wrap '=' guarded by (col u>2048) when mainC (R4 clobber lesson).
__global__ __launch_bounds__(256) void attn_mfma_kernel(
    const ushort* __restrict__ qb, const ushort* __restrict__ kv,
    const ushort* __restrict__ vt, const ushort* __restrict__ Qr,
    const ushort* __restrict__ maskb, ushort* __restrict__ attn) {
  __shared__ ushort qA[33][72];        // q rows s0b..s0b+32
  __shared__ float Btf[4][16][85];     // per-wave B-hat scratch
  __shared__ ushort Pw[4][16][72];     // per-wave P (bf16, A-frag readable)
  __shared__ float csum[32];

  const int s0b = blockIdx.x * 32;
  const int h = blockIdx.y;
  const int b = blockIdx.z;
  const int tid = threadIdx.x;
  const int w = tid >> 6, lane = tid & 63, m15 = lane & 15, q4 = lane >> 4;
  const int st = w & 1, th = w >> 1;
  const int s0w = s0b + st * 16;

  for (int idx = tid; idx < 33 * 8; idx += 256) {
    int r = idx >> 3, cc = (idx & 7) * 8;
    int srow = s0b + r;
    uint4 v = make_uint4(0u, 0u, 0u, 0u);
    if (srow < SEQ)
      v = *(const uint4*)(&qb[((b << 10) + srow) * D_MODEL + (h << 6) + cc]);
    *(uint4*)(&qA[r][cc]) = v;
  }
  __syncthreads();

  float* Bt = &Btf[w][0][0];
  ushort* Pp = &Pw[w][0][0];

  const short8 afr0 = *(const short8*)(&qA[st * 16 + m15][q4 * 8]);
  const short8 afr1 = *(const short8*)(&qA[st * 16 + m15][32 + q4 * 8]);
  const short8 awr0 = *(const short8*)(&qA[st * 16 + m15 + 1][q4 * 8]);
  const short8 awr1 = *(const short8*)(&qA[st * 16 + m15 + 1][32 + q4 * 8]);

  float4v oacc[4] = {};
  float lsum4[4] = {0.f, 0.f, 0.f, 0.f};

  for (int ci = 0; ci < 16; ++ci) {
    const int t0 = th * 1024 + ci * 64;
    const int umin = t0 - s0w + 1008;
    const bool mainC = (umin <= TOT - 1);
    const bool wrapC = (umin >= 1971);

    // mask (pre-scaled bf16) for this chunk
    float mreg[16];
#pragma unroll
    for (int nt = 0; nt < 4; ++nt)
#pragma unroll
      for (int i = 0; i < 4; ++i)
        mreg[nt * 4 + i] =
            b2f(maskb[(s0w + q4 * 4 + i) * TOT + t0 + nt * 16 + m15]);

    // ---- A-term: 16 x 64 QK^T, K frags direct from global ----
    float4v aacc[4];
#pragma unroll
    for (int nt = 0; nt < 4; ++nt) {
      const ushort* kp =
          &kv[((b << 11) + t0 + nt * 16 + m15) * 2048 + (h << 6) + q4 * 8];
      short8 k0 = *(const short8*)kp;
      short8 k1 = *(const short8*)(kp + 32);
      float4v c = {0.f, 0.f, 0.f, 0.f};
      c = __builtin_amdgcn_mfma_f32_16x16x32_bf16(afr0, k0, c, 0, 0, 0);
      c = __builtin_amdgcn_mfma_f32_16x16x32_bf16(afr1, k1, c, 0, 0, 0);
      aacc[nt] = c;
    }

    // ---- B-term main: 16 x 80 window, scatter '=' into Bt ----
    if (mainC) {
#pragma unroll
      for (int nt = 0; nt < 5; ++nt) {
        int u = umin + nt * 16 + m15;
        short8 w0 = {0, 0, 0, 0, 0, 0, 0, 0}, w1 = w0;
        if (u < TOT) {
          const ushort* p = &Qr[u * D_MODEL + (h << 6) + q4 * 8];
          w0 = *(const short8*)p;
          w1 = *(const short8*)(p + 32);
        }
        float4v c = {0.f, 0.f, 0.f, 0.f};
        c = __builtin_amdgcn_mfma_f32_16x16x32_bf16(afr0, w0, c, 0, 0, 0);
        c = __builtin_amdgcn_mfma_f32_16x16x32_bf16(afr1, w1, c, 0, 0, 0);
#pragma unroll
        for (int i = 0; i < 4; ++i)
          Bt[(q4 * 4 + i) * 85 + nt * 16 + m15] = c[i];
      }
    }
    // ---- B-term wrap ----
    if (wrapC) {
#pragma unroll
      for (int nt = 0; nt < 5; ++nt) {
        int j = umin + nt * 16 + m15 - (TOT + 1);
        short8 w0 = {0, 0, 0, 0, 0, 0, 0, 0}, w1 = w0;
        if (j >= 0) {
          const ushort* p = &Qr[j * D_MODEL + (h << 6) + q4 * 8];
          w0 = *(const short8*)p;
          w1 = *(const short8*)(p + 32);
        }
        float4v c = {0.f, 0.f, 0.f, 0.f};
        c = __builtin_amdgcn_mfma_f32_16x16x32_bf16(awr0, w0, c, 0, 0, 0);
        c = __builtin_amdgcn_mfma_f32_16x16x32_bf16(awr1, w1, c, 0, 0, 0);
        bool wr = (!mainC) || (j >= 0);
#pragma unroll
        for (int i = 0; i < 4; ++i)
          if (wr) Bt[(q4 * 4 + i) * 85 + nt * 16 + m15] = c[i];
      }
    }

    // ---- scores -> exp -> Pp; row sums via shuffle ----
    float psum[4] = {0.f, 0.f, 0.f, 0.f};
#pragma unroll
    for (int nt = 0; nt < 4; ++nt)
#pragma unroll
      for (int i = 0; i < 4; ++i) {
        int sl = q4 * 4 + i, tl = nt * 16 + m15;
        float bv = Bt[sl * 85 + (tl - sl + 15)];
        float p = __expf((aacc[nt][i] + bv) * 0.125f + mreg[nt * 4 + i]);
        psum[i] += p;
        Pp[sl * 72 + tl] = f2b(p);
      }
#pragma unroll
    for (int i = 0; i < 4; ++i) {
      float v = psum[i];
      v += __shfl_xor(v, 1, 64);
      v += __shfl_xor(v, 2, 64);
      v += __shfl_xor(v, 4, 64);
      v += __shfl_xor(v, 8, 64);
      lsum4[i] += v;
    }

    // ---- PV: P A-frags from Pp, V frags direct from vt ----
    short8 pfr0 = *(const short8*)(&Pp[m15 * 72 + q4 * 8]);
    short8 pfr1 = *(const short8*)(&Pp[m15 * 72 + 32 + q4 * 8]);
#pragma unroll
    for (int nd = 0; nd < 4; ++nd) {
      const ushort* vp =
          &vt[((b << 10) + (h << 6) + nd * 16 + m15) * 2048 + t0 + q4 * 8];
      short8 v0 = *(const short8*)vp;
      short8 v1 = *(const short8*)(vp + 32);
      oacc[nd] = __builtin_amdgcn_mfma_f32_16x16x32_bf16(pfr0, v0, oacc[nd], 0, 0, 0);
      oacc[nd] = __builtin_amdgcn_mfma_f32_16x16x32_bf16(pfr1, v1, oacc[nd], 0, 0, 0);
    }
  }

  // ---- combine the two T-halves, normalize, store ----
  __syncthreads();
  float* comb = &Btf[0][0][0];   // reuse scratch: [2][16][65]
  if (th == 1) {
#pragma unroll
    for (int nd = 0; nd < 4; ++nd)
#pragma unroll
      for (int i = 0; i < 4; ++i)
        comb[(st * 16 + q4 * 4 + i) * 65 + nd * 16 + m15] = oacc[nd][i];
    if (m15 == 0)
#pragma unroll
      for (int i = 0; i < 4; ++i) csum[st * 16 + q4 * 4 + i] = lsum4[i];
  }
  __syncthreads();
  if (th == 0) {
#pragma unroll
    for (int i = 0; i < 4; ++i) lsum4[i] += csum[st * 16 + q4 * 4 + i];
#pragma unroll
    for (int nd = 0; nd < 4; ++nd)
#pragma unroll
      for (int i = 0; i < 4; ++i) {
        int sl = q4 * 4 + i;
        float v = oacc[nd][i] + comb[(st * 16 + sl) * 65 + nd * 16 + m15];
        attn[((b << 10) + s0w + sl) * D_MODEL + (h << 6) + nd * 16 + m15] =
            f2b(v / lsum4[i]);
      }
  }
}

// ---------------------------------------------------------------- launch ----
extern "C" void kernel_launch(void* const* d_in, const int* in_sizes, int n_in,
                              void* d_out, int out_size, void* d_ws,
                              size_t ws_size, hipStream_t stream) {
  const float* x = (const float*)d_in[0];
  const float* mem = (const float*)d_in[1];
  const float* mask = (const float*)d_in[2];
  const float* rel = (const float*)d_in[3];
  const float* Wq = (const float*)d_in[4];
  const float* bq = (const float*)d_in[5];
  const float* Wke = (const float*)d_in[6];
  const float* bke = (const float*)d_in[7];
  const float* Wkr = (const float*)d_in[8];
  const float* bkr = (const float*)d_in[9];
  const float* Wv = (const float*)d_in[10];
  const float* bv = (const float*)d_in[11];
  const float* Wo = (const float*)d_in[12];
  const float* bo = (const float*)d_in[13];
  float* out = (float*)d_out;

  ushort* ws = (ushort*)d_ws;
  ushort* xt = ws;                          // 4096x1024 (later reused as vt)
  ushort* xbrel = xt + 4096 * 1024;         // [xb(2048); relb(2048)] x 1024
  ushort* WqT = xbrel + 4096 * 1024;
  ushort* WkeT = WqT + 1024 * 1024;
  ushort* WvT = WkeT + 1024 * 1024;         // adjacent to WkeT (KV concat)
  ushort* WkrT = WvT + 1024 * 1024;
  ushort* WoT = WkrT + 1024 * 1024;
  ushort* kv = WoT + 1024 * 1024;           // 4096x2048 (K cols 0..1023, V 1024..)
  ushort* qr = kv + 4096 * 2048;            // [qbuf(2048); Qrb(2048)] x 1024
  ushort* attn = qr + 4096 * 1024;          // 2048x1024
  ushort* maskb = attn + 2048 * 1024;       // 1024x2048 bf16 pre-scaled
  ushort* relb = xbrel + 2048 * 1024;
  ushort* Qrb = qr + 2048 * 1024;
  ushort* vt = xt;                          // overlay: xt dead after KV GEMM

  concat_cvt_kernel<<<2048, 256, 0, stream>>>(x, mem, xt, xbrel);
  cvt_kernel<<<1024, 256, 0, stream>>>(rel, relb);
  maskcvt_kernel<<<1024, 256, 0, stream>>>(mask, maskb);
  transpose_cvt5_kernel<<<dim3(32, 32, 5), 256, 0, stream>>>(
      Wq, Wke, Wkr, Wv, Wo, WqT, WkeT, WkrT, WvT, WoT);

  // K|V fused projection: xt(4096) @ [WkeT;WvT]^T -> kv (N=2048)
  gemm128_kernel<<<dim3(32, 16), 256, 0, stream>>>(xt, WkeT, bke, bv, kv,
                                                   4096, 2048, 1024);
  // q | Qrel fused projection: [xb;relb](4096) with per-row-half B
  gemm64_kernel<0><<<dim3(64, 8), 256, 0, stream>>>(
      xbrel, WqT, WkrT, 2048, bq, bkr, qr, 4096, 1024, 1024);
  // V transpose -> vt[b][d][t] (coalesced both sides)
  vtrans_kernel<<<dim3(128, 16), 256, 0, stream>>>(kv, vt);

  attn_mfma_kernel<<<dim3(SEQ / 32, NH, BATCH), 256, 0, stream>>>(
      qr, kv, vt, Qrb, maskb, attn);

  gemm64_kernel<1><<<dim3(32, 8), 256, 0, stream>>>(
      attn, WoT, WoT, 1 << 30, bo, bo, out, 2048, 1024, 1024);
}

// Round 7
// 365.898 us; speedup vs baseline: 1.1854x; 1.1854x over previous
//
#include <hip/hip_runtime.h>

typedef unsigned short ushort;
typedef unsigned int uint;
typedef __attribute__((ext_vector_type(8))) short short8;
typedef __attribute__((ext_vector_type(4))) float float4v;

#define D_MODEL 1024
#define NH 16
#define DH 64
#define BATCH 2
#define SEQ 1024
#define MEMLEN 1024
#define TOT 2048

__device__ __forceinline__ float b2f(ushort u) {
  return __uint_as_float(((uint)u) << 16);
}
__device__ __forceinline__ ushort f2b(float f) {
  uint i = __float_as_uint(f);
  uint r = (i + 0x7fffu + ((i >> 16) & 1u)) >> 16;
  return (ushort)r;
}
__device__ __forceinline__ void gld16(const ushort* g, ushort* l) {
  __builtin_amdgcn_global_load_lds(
      (const __attribute__((address_space(1))) void*)g,
      (__attribute__((address_space(3))) void*)l, 16, 0, 0);
}

// ------------------------------------------------- concat + cast to bf16 ----
__global__ __launch_bounds__(256) void concat_cvt_kernel(
    const float* __restrict__ x, const float* __restrict__ mem,
    ushort* __restrict__ xt, ushort* __restrict__ xb) {
  int idx = blockIdx.x * 256 + threadIdx.x;
  int row = idx >> 7;
  int c8 = (idx & 127) << 3;
  int b = row >> 11;
  int i = row & 2047;
  const float* src = (i < MEMLEN) ? &mem[((b << 10) + i) * D_MODEL]
                                  : &x[((b << 10) + (i - MEMLEN)) * D_MODEL];
  float4 f0 = *(const float4*)(&src[c8]);
  float4 f1 = *(const float4*)(&src[c8 + 4]);
  ushort u[8] = {f2b(f0.x), f2b(f0.y), f2b(f0.z), f2b(f0.w),
                 f2b(f1.x), f2b(f1.y), f2b(f1.z), f2b(f1.w)};
  *(uint4*)(&xt[row * D_MODEL + c8]) = *(const uint4*)u;
  if (i >= MEMLEN)
    *(uint4*)(&xb[((b << 10) + (i - MEMLEN)) * D_MODEL + c8]) = *(const uint4*)u;
}

// --------------------------------------------------- fp32 -> bf16 cast ------
__global__ __launch_bounds__(256) void cvt_kernel(const float* __restrict__ in,
                                                  ushort* __restrict__ out) {
  int idx = blockIdx.x * 256 + threadIdx.x;
  int base = idx << 3;
  float4 f0 = *(const float4*)(&in[base]);
  float4 f1 = *(const float4*)(&in[base + 4]);
  ushort u[8] = {f2b(f0.x), f2b(f0.y), f2b(f0.z), f2b(f0.w),
                 f2b(f1.x), f2b(f1.y), f2b(f1.z), f2b(f1.w)};
  *(uint4*)(&out[base]) = *(const uint4*)u;
}

// --------------------- mask -> bf16 pre-multiplied by -1e9 ------------------
__global__ __launch_bounds__(256) void maskcvt_kernel(
    const float* __restrict__ in, ushort* __restrict__ out) {
  int idx = blockIdx.x * 256 + threadIdx.x;
  int base = idx << 3;
  float4 f0 = *(const float4*)(&in[base]);
  float4 f1 = *(const float4*)(&in[base + 4]);
  ushort u[8] = {f2b(f0.x * -1e9f), f2b(f0.y * -1e9f), f2b(f0.z * -1e9f),
                 f2b(f0.w * -1e9f), f2b(f1.x * -1e9f), f2b(f1.y * -1e9f),
                 f2b(f1.z * -1e9f), f2b(f1.w * -1e9f)};
  *(uint4*)(&out[base]) = *(const uint4*)u;
}

// --------------------------- 5x transpose + cast to bf16 (one launch) -------
__global__ __launch_bounds__(256) void transpose_cvt5_kernel(
    const float* __restrict__ W0, const float* __restrict__ W1,
    const float* __restrict__ W2, const float* __restrict__ W3,
    const float* __restrict__ W4, ushort* __restrict__ T0,
    ushort* __restrict__ T1, ushort* __restrict__ T2, ushort* __restrict__ T3,
    ushort* __restrict__ T4) {
  __shared__ ushort tle[32][33];
  const float* W;
  ushort* T;
  switch (blockIdx.z) {
    case 0: W = W0; T = T0; break;
    case 1: W = W1; T = T1; break;
    case 2: W = W2; T = T2; break;
    case 3: W = W3; T = T3; break;
    default: W = W4; T = T4; break;
  }
  const int bx = blockIdx.x * 32, by = blockIdx.y * 32;
  const int tx = threadIdx.x & 31, ty = threadIdx.x >> 5;
#pragma unroll
  for (int j = 0; j < 32; j += 8)
    tle[ty + j][tx] = f2b(W[(by + ty + j) * 1024 + bx + tx]);
  __syncthreads();
#pragma unroll
  for (int j = 0; j < 32; j += 8)
    T[(bx + ty + j) * 1024 + by + tx] = tle[tx][ty + j];
}

// ------------------------------------- V transpose: kv cols -> vt[b][d][t] --
__global__ __launch_bounds__(256) void vtrans_kernel(
    const ushort* __restrict__ kv, ushort* __restrict__ vt) {
  __shared__ ushort tle[32][76];
  const int gx = blockIdx.x;   // 32-row (b,t) tiles
  const int gy = blockIdx.y;   // 64-wide d tiles
  const int tid = threadIdx.x;
  const int r = tid >> 3, c8 = (tid & 7) * 8;
  *(uint4*)(&tle[r][c8]) =
      *(const uint4*)(&kv[(gx * 32 + r) * 2048 + 1024 + gy * 64 + c8]);
  __syncthreads();
  const int dr = tid >> 2, tc8 = (tid & 3) * 8;
  const int bb = (gx * 32) >> 11, tbase = (gx * 32) & 2047;
  ushort tmp[8];
#pragma unroll
  for (int j = 0; j < 8; ++j) tmp[j] = tle[tc8 + j][dr];
  *(uint4*)(&vt[((bb << 10) + gy * 64 + dr) * 2048 + tbase + tc8]) =
      *(const uint4*)tmp;
}

// -------------------------------------------------- 128x128 m97-style GEMM --
// KV projection: cols<1024 = K (scaled 0.125 with bke), cols>=1024 = V (bv).
__global__ __launch_bounds__(256) void gemm128_kernel(
    const ushort* __restrict__ A, const ushort* __restrict__ BT,
    const float* __restrict__ b0, const float* __restrict__ b1,
    ushort* __restrict__ Cout, int M, int N, int K) {
  __shared__ ushort As[128 * 32];
  __shared__ ushort Bs[128 * 32];
  const int m0 = blockIdx.x * 128, n0 = blockIdx.y * 128;
  const int tid = threadIdx.x;
  const int w = tid >> 6, lane = tid & 63, m15 = lane & 15, q4 = lane >> 4;
  const int wm = w & 1, wn = w >> 1;
  float4v acc[4][4] = {};
  const int c0 = tid, c1 = tid + 256;
  const int r0 = c0 >> 2, u0 = (c0 & 3) * 8;
  const int r1 = c1 >> 2, u1 = (c1 & 3) * 8;

  for (int kk = 0; kk < K; kk += 32) {
    __syncthreads();
    gld16(&A[(m0 + r0) * K + kk + u0], &As[c0 * 8]);
    gld16(&A[(m0 + r1) * K + kk + u1], &As[c1 * 8]);
    gld16(&BT[(n0 + r0) * K + kk + u0], &Bs[c0 * 8]);
    gld16(&BT[(n0 + r1) * K + kk + u1], &Bs[c1 * 8]);
    __syncthreads();
    short8 af[4], bf[4];
#pragma unroll
    for (int i = 0; i < 4; ++i)
      af[i] = *(const short8*)(&As[(wm * 64 + i * 16 + m15) * 32 + q4 * 8]);
#pragma unroll
    for (int j = 0; j < 4; ++j)
      bf[j] = *(const short8*)(&Bs[(wn * 64 + j * 16 + m15) * 32 + q4 * 8]);
#pragma unroll
    for (int i = 0; i < 4; ++i)
#pragma unroll
      for (int j = 0; j < 4; ++j)
        acc[i][j] =
            __builtin_amdgcn_mfma_f32_16x16x32_bf16(af[i], bf[j], acc[i][j], 0, 0, 0);
  }
#pragma unroll
  for (int j = 0; j < 4; ++j) {
    int col = n0 + wn * 64 + j * 16 + m15;
    float bv = (col < 1024) ? b0[col] : b1[col - 1024];
    float sc = (col < 1024) ? 0.125f : 1.0f;   // pre-scale K by 1/8 (exact)
#pragma unroll
    for (int i = 0; i < 4; ++i) {
      int rowb = m0 + wm * 64 + i * 16 + q4 * 4;
#pragma unroll
      for (int r = 0; r < 4; ++r)
        Cout[(rowb + r) * N + col] = f2b((acc[i][j][r] + bv) * sc);
    }
  }
}

// -------------------------------------- 64x128-tile GEMM (for small M) ------
template <int EPI>
__global__ __launch_bounds__(256) void gemm64_kernel(
    const ushort* __restrict__ A, const ushort* __restrict__ BT0,
    const ushort* __restrict__ BT1, int rowSplit, const float* __restrict__ b0,
    const float* __restrict__ b1, void* __restrict__ Cout, int M, int N, int K) {
  __shared__ ushort As[64 * 32];
  __shared__ ushort Bs[128 * 32];
  const int m0 = blockIdx.x * 64, n0 = blockIdx.y * 128;
  const ushort* BT = (m0 < rowSplit) ? BT0 : BT1;
  const float* bias = (m0 < rowSplit) ? b0 : b1;
  const int tid = threadIdx.x;
  const int w = tid >> 6, lane = tid & 63, m15 = lane & 15, q4 = lane >> 4;
  float4v acc[4][2] = {};
  const int ra = tid >> 2, ua = (tid & 3) * 8;
  const int c0 = tid, c1 = tid + 256;
  const int rb0 = c0 >> 2, ub0 = (c0 & 3) * 8;
  const int rb1 = c1 >> 2, ub1 = (c1 & 3) * 8;

  for (int kk = 0; kk < K; kk += 32) {
    __syncthreads();
    gld16(&A[(m0 + ra) * K + kk + ua], &As[tid * 8]);
    gld16(&BT[(n0 + rb0) * K + kk + ub0], &Bs[c0 * 8]);
    gld16(&BT[(n0 + rb1) * K + kk + ub1], &Bs[c1 * 8]);
    __syncthreads();
    short8 bf[2];
#pragma unroll
    for (int j = 0; j < 2; ++j)
      bf[j] = *(const short8*)(&Bs[(w * 32 + j * 16 + m15) * 32 + q4 * 8]);
#pragma unroll
    for (int i = 0; i < 4; ++i) {
      short8 af = *(const short8*)(&As[(i * 16 + m15) * 32 + q4 * 8]);
#pragma unroll
      for (int j = 0; j < 2; ++j)
        acc[i][j] =
            __builtin_amdgcn_mfma_f32_16x16x32_bf16(af, bf[j], acc[i][j], 0, 0, 0);
    }
  }
#pragma unroll
  for (int j = 0; j < 2; ++j) {
    int col = n0 + w * 32 + j * 16 + m15;
    float bv = bias[col];
#pragma unroll
    for (int i = 0; i < 4; ++i) {
      int rowb = m0 + i * 16 + q4 * 4;
#pragma unroll
      for (int r = 0; r < 4; ++r) {
        float v = acc[i][j][r] + bv;
        if (EPI == 1)
          ((float*)Cout)[(rowb + r) * N + col] = v;
        else
          ((ushort*)Cout)[(rowb + r) * N + col] = f2b(v);
      }
    }
  }
}

// ----------------------- Bhat batched GEMM: Bh[b,h,s,u] = 0.125 q.Qrel ------
// Per h: A = q[b*1024+s, h*64:+64], B = Qrel[u, h*64:+64], K=64 single stage.
// LDS halves stored k-major (As[kh][128][32]) to keep stride-32 frag rows.
__global__ __launch_bounds__(256) void bhat_kernel(
    const ushort* __restrict__ q, const ushort* __restrict__ Qrb,
    ushort* __restrict__ Bh) {
  __shared__ ushort As[2 * 128 * 32];
  __shared__ ushort Bs[2 * 128 * 32];
  const int bs0 = blockIdx.x * 128, u0 = blockIdx.y * 128, h = blockIdx.z;
  const int tid = threadIdx.x;
  const int w = tid >> 6, lane = tid & 63, m15 = lane & 15, q4 = lane >> 4;
  const int wm = w & 1, wn = w >> 1;

#pragma unroll
  for (int c = 0; c < 4; ++c) {
    int unit = c * 256 + tid;               // flat LDS ushort = unit*8
    int row = (unit >> 2) & 127, kh = unit >> 9, cu = unit & 3;
    gld16(&q[(bs0 + row) * 1024 + (h << 6) + kh * 32 + cu * 8], &As[unit * 8]);
    gld16(&Qrb[(u0 + row) * 1024 + (h << 6) + kh * 32 + cu * 8], &Bs[unit * 8]);
  }
  __syncthreads();

  float4v acc[4][4] = {};
#pragma unroll
  for (int kh = 0; kh < 2; ++kh) {
    short8 af[4], bf[4];
#pragma unroll
    for (int i = 0; i < 4; ++i)
      af[i] = *(const short8*)(&As[kh * 4096 + (wm * 64 + i * 16 + m15) * 32 + q4 * 8]);
#pragma unroll
    for (int j = 0; j < 4; ++j)
      bf[j] = *(const short8*)(&Bs[kh * 4096 + (wn * 64 + j * 16 + m15) * 32 + q4 * 8]);
#pragma unroll
    for (int i = 0; i < 4; ++i)
#pragma unroll
      for (int j = 0; j < 4; ++j)
        acc[i][j] =
            __builtin_amdgcn_mfma_f32_16x16x32_bf16(af[i], bf[j], acc[i][j], 0, 0, 0);
  }
  const int b = bs0 >> 10;
  const int outrow0 = ((b << 4) + h) * 1024 + (bs0 & 1023);
#pragma unroll
  for (int j = 0; j < 4; ++j) {
    int col = u0 + wn * 64 + j * 16 + m15;
#pragma unroll
    for (int i = 0; i < 4; ++i) {
      int rowb = outrow0 + wm * 64 + i * 16 + q4 * 4;
#pragma unroll
      for (int r = 0; r < 4; ++r)
        Bh[(rowb + r) * 2048 + col] = f2b(acc[i][j][r] * 0.125f);
    }
  }
}

// ----------------- fused attention: QK + Bhat gather + exp + PV -------------
// Wave-independent: wave = (st s-tile 16 rows, th T-half). Chunks of 32 t.
// ZERO barriers in the loop: K/V/mask loaded per chunk (issued at top),
// Bhat gathered one chunk ahead; wave-private Pp LDS for C->A transform.
// u = t-s+1023: u<=2047 -> Bh[s][u]; u==2048 -> 0; u>=2049 -> Bh[s+1][u-2049].
__global__ __launch_bounds__(256) void attn_kernel(
    const ushort* __restrict__ qb, const ushort* __restrict__ kv,
    const ushort* __restrict__ vt, const ushort* __restrict__ Bh,
    const ushort* __restrict__ maskb, ushort* __restrict__ attn) {
  __shared__ ushort Pp[4][16 * 36];
  __shared__ float comb[2][16][68];
  __shared__ float csum[32];

  const int tid = threadIdx.x;
  const int w = tid >> 6, lane = tid & 63, m15 = lane & 15, q4 = lane >> 4;
  const int st = w & 1, th = w >> 1;
  const int s0w = blockIdx.x * 32 + st * 16;
  const int h = blockIdx.y, b = blockIdx.z;
  const int s_l = q4 * 4;

  const ushort* qp = &qb[((b << 10) + s0w + m15) * 1024 + (h << 6) + q4 * 8];
  const short8 af0 = *(const short8*)qp;
  const short8 af1 = *(const short8*)(qp + 32);

  const ushort* kvb = &kv[((size_t)(b << 11) * 2048) + (h << 6)];
  const ushort* vtb = &vt[((size_t)((b << 10) + (h << 6))) * 2048];
  const int bhbase = ((b << 4) + h) << 21;   // *(1024*2048)
  ushort* pw = &Pp[w][0];

  ushort bhr[8];
  auto pre_bh = [&](int t0) {
#pragma unroll
    for (int nt = 0; nt < 2; ++nt)
#pragma unroll
      for (int i = 0; i < 4; ++i) {
        int s = s0w + s_l + i;
        int t = t0 + nt * 16 + m15;
        int u = t - s + 1023;
        int row = (u <= 2047) ? s : (s + 1);
        int uu = (u <= 2047) ? u : (u - 2049);
        ushort v = Bh[bhbase + (row << 11) + uu];
        bhr[nt * 4 + i] = (u == 2048) ? (ushort)0 : v;
      }
  };

  float lsum4[4] = {0.f, 0.f, 0.f, 0.f};
  float4v oacc[4] = {};
  pre_bh(th * 1024);   // chunk 0

  for (int ci = 0; ci < 32; ++ci) {
    const int t0 = th * 1024 + ci * 32;
    // current-chunk loads (issued up front; consumed after MFMA/addr work)
    short8 Kr[2][2], Vr[4];
    ushort mk[8];
#pragma unroll
    for (int nt = 0; nt < 2; ++nt) {
      const ushort* kp = &kvb[(size_t)(t0 + nt * 16 + m15) * 2048 + q4 * 8];
      Kr[nt][0] = *(const short8*)kp;
      Kr[nt][1] = *(const short8*)(kp + 32);
    }
#pragma unroll
    for (int nd = 0; nd < 4; ++nd)
      Vr[nd] = *(const short8*)(&vtb[(size_t)(nd * 16 + m15) * 2048 + t0 + q4 * 8]);
#pragma unroll
    for (int nt = 0; nt < 2; ++nt)
#pragma unroll
      for (int i = 0; i < 4; ++i)
        mk[nt * 4 + i] = maskb[(s0w + s_l + i) * 2048 + t0 + nt * 16 + m15];
    // stash this chunk's Bhat; prefetch next chunk's
    ushort bhc[8];
#pragma unroll
    for (int j = 0; j < 8; ++j) bhc[j] = bhr[j];
    if (ci < 31) pre_bh(t0 + 32);

    // scores -> exp -> Pp (wave-private, in-order: no barrier)
#pragma unroll
    for (int nt = 0; nt < 2; ++nt) {
      float4v a = {0.f, 0.f, 0.f, 0.f};
      a = __builtin_amdgcn_mfma_f32_16x16x32_bf16(af0, Kr[nt][0], a, 0, 0, 0);
      a = __builtin_amdgcn_mfma_f32_16x16x32_bf16(af1, Kr[nt][1], a, 0, 0, 0);
#pragma unroll
      for (int i = 0; i < 4; ++i) {
        float p = __expf(a[i] + b2f(bhc[nt * 4 + i]) + b2f(mk[nt * 4 + i]));
        lsum4[i] += p;
        pw[(s_l + i) * 36 + nt * 16 + m15] = f2b(p);
      }
    }
    // PV
    short8 pfr = *(const short8*)(&pw[m15 * 36 + q4 * 8]);
#pragma unroll
    for (int nd = 0; nd < 4; ++nd)
      oacc[nd] = __builtin_amdgcn_mfma_f32_16x16x32_bf16(pfr, Vr[nd], oacc[nd], 0, 0, 0);
  }

  // row sums across the 16 t-lanes (m15 butterfly)
#pragma unroll
  for (int i = 0; i < 4; ++i) {
    float v = lsum4[i];
    v += __shfl_xor(v, 1, 64);
    v += __shfl_xor(v, 2, 64);
    v += __shfl_xor(v, 4, 64);
    v += __shfl_xor(v, 8, 64);
    lsum4[i] = v;
  }
  // combine T-halves
  if (th == 1) {
#pragma unroll
    for (int nd = 0; nd < 4; ++nd)
#pragma unroll
      for (int i = 0; i < 4; ++i)
        comb[st][s_l + i][nd * 16 + m15] = oacc[nd][i];
    if (m15 == 0)
#pragma unroll
      for (int i = 0; i < 4; ++i) csum[st * 16 + s_l + i] = lsum4[i];
  }
  __syncthreads();
  if (th == 0) {
#pragma unroll
    for (int i = 0; i < 4; ++i) lsum4[i] += csum[st * 16 + s_l + i];
#pragma unroll
    for (int nd = 0; nd < 4; ++nd)
#pragma unroll
      for (int i = 0; i < 4; ++i) {
        float v = oacc[nd][i] + comb[st][s_l + i][nd * 16 + m15];
        attn[((b << 10) + s0w + s_l + i) * 1024 + (h << 6) + nd * 16 + m15] =
            f2b(v / lsum4[i]);
      }
  }
}

// ---------------------------------------------------------------- launch ----
extern "C" void kernel_launch(void* const* d_in, const int* in_sizes, int n_in,
                              void* d_out, int out_size, void* d_ws,
                              size_t ws_size, hipStream_t stream) {
  const float* x = (const float*)d_in[0];
  const float* mem = (const float*)d_in[1];
  const float* mask = (const float*)d_in[2];
  const float* rel = (const float*)d_in[3];
  const float* Wq = (const float*)d_in[4];
  const float* bq = (const float*)d_in[5];
  const float* Wke = (const float*)d_in[6];
  const float* bke = (const float*)d_in[7];
  const float* Wkr = (const float*)d_in[8];
  const float* bkr = (const float*)d_in[9];
  const float* Wv = (const float*)d_in[10];
  const float* bv = (const float*)d_in[11];
  const float* Wo = (const float*)d_in[12];
  const float* bo = (const float*)d_in[13];
  float* out = (float*)d_out;

  ushort* ws = (ushort*)d_ws;
  ushort* xt = ws;                          // 4096x1024 (reused as vt)
  ushort* xbrel = xt + 4096 * 1024;         // [xb(2048); relb(2048)] x 1024
  ushort* WqT = xbrel + 4096 * 1024;
  ushort* WkeT = WqT + 1024 * 1024;
  ushort* WvT = WkeT + 1024 * 1024;
  ushort* WkrT = WvT + 1024 * 1024;
  ushort* WoT = WkrT + 1024 * 1024;
  ushort* kv = WoT + 1024 * 1024;           // 4096x2048 (K cols 0..1023 scaled, V 1024..)
  ushort* qr = kv + 4096 * 2048;            // [qbuf(2048); Qrb(2048)] x 1024
  ushort* attn = qr + 4096 * 1024;          // 2048x1024
  ushort* maskb = attn + 2048 * 1024;       // 1024x2048 bf16 pre-scaled
  ushort* Bh = maskb + 1024 * 2048;         // [b*16+h][1024 s][2048 u] bf16 (128 MB)
  ushort* relb = xbrel + 2048 * 1024;
  ushort* Qrb = qr + 2048 * 1024;
  ushort* vt = xt;

  concat_cvt_kernel<<<2048, 256, 0, stream>>>(x, mem, xt, xbrel);
  cvt_kernel<<<1024, 256, 0, stream>>>(rel, relb);
  maskcvt_kernel<<<1024, 256, 0, stream>>>(mask, maskb);
  transpose_cvt5_kernel<<<dim3(32, 32, 5), 256, 0, stream>>>(
      Wq, Wke, Wkr, Wv, Wo, WqT, WkeT, WkrT, WvT, WoT);

  gemm128_kernel<<<dim3(32, 16), 256, 0, stream>>>(xt, WkeT, bke, bv, kv,
                                                   4096, 2048, 1024);
  gemm64_kernel<0><<<dim3(64, 8), 256, 0, stream>>>(
      xbrel, WqT, WkrT, 2048, bq, bkr, qr, 4096, 1024, 1024);
  vtrans_kernel<<<dim3(128, 16), 256, 0, stream>>>(kv, vt);

  bhat_kernel<<<dim3(16, 16, 16), 256, 0, stream>>>(qr, Qrb, Bh);

  attn_kernel<<<dim3(SEQ / 32, NH, BATCH), 256, 0, stream>>>(
      qr, kv, vt, Bh, maskb, attn);

  gemm64_kernel<1><<<dim3(32, 8), 256, 0, stream>>>(
      attn, WoT, WoT, 1 << 30, bo, bo, out, 2048, 1024, 1024);
}